// Round 6
// baseline (294.382 us; speedup 1.0000x reference)
//
#include <hip/hip_runtime.h>

#define NXD 512
#define NYD 512
#define CD  64
#define NPIX (NXD * NYD)
// Problem constants fixed by the reference: B=4, C=64, NX=NY=512.
//
// Measured lessons:
//  R3: per-thread 64-channel sweep (64 x 1MB-strided store streams per wave)
//      destroyed DRAM write locality: kernels ~79 -> ~155 us. Keep stores
//      linear-ish: few streams per thread, 1 KB/wave per instruction.
//  R5: nt stores neutral vs R2 — headline variance is the harness poison-fill
//      clock lottery (1 GiB fill: 166-224 us). Judge by decomposition.
//  R6: 4 channels/thread — one float4 feat load serves 4 channels (scattered
//      line traffic /4), winner int4 amortized /4; 4 store streams per thread.

typedef float nfloat4 __attribute__((ext_vector_type(4)));

// Init winner array to -1 (int4 stores). 4 MiB.
__global__ void ppscatter_init_winner(int4* __restrict__ win4, int n_win4) {
    int i = blockIdx.x * blockDim.x + threadIdx.x;
    if (i < n_win4) win4[i] = make_int4(-1, -1, -1, -1);
}

// Last-write-wins vote: max voxel index per flat slot wins (matches numpy
// fancy-assignment last-duplicate-wins; verified absmax=0.0 rounds 1-5).
__global__ void ppscatter_vote(const int* __restrict__ coords, int n,
                               int* __restrict__ winner) {
    int v = blockIdx.x * blockDim.x + threadIdx.x;
    if (v >= n) return;
    int b = coords[3 * v + 0];
    int x = coords[3 * v + 1];
    int y = coords[3 * v + 2];
    atomicMax(&winner[b * NPIX + x * NYD + y], v);
}

// Gather: one thread per (pixel-group, channel-group-of-4).
//   t bits: y4 [0:6], x [7:15], cg [16:19], b [20:21]   (4,194,304 threads)
//   out4 idx for channel 4*cg+k: (b<<22) | (cg<<18) | (k<<16) | (x<<7) | y4
// Per wave each of the 4 stores is 1 KB contiguous; per block: 4 chunks of
// 4 KB spaced 1 MB — ~2.5k write streams chip-wide (R3's failure mode was
// ~41k). Feat read: one float4 per hit pixel covers 4 channels.
__global__ void ppscatter_gather(const float4* __restrict__ feat4,
                                 const int4* __restrict__ win4,
                                 nfloat4* __restrict__ out4) {
    int t = blockIdx.x * blockDim.x + threadIdx.x;
    int y4x = t & 0xFFFF;             // y4(7) + x(9)
    int cg  = (t >> 16) & 15;         // channel group (4 channels)
    int b   = t >> 20;

    int4 w = win4[(b << 16) | y4x];
    int base = (b << 22) | (cg << 18) | y4x;   // out4 index at k=0

    nfloat4 v0 = {0.f, 0.f, 0.f, 0.f}, v1 = v0, v2 = v0, v3 = v0;
    // Empty fast path: entries are -1 or >=0; AND == -1 iff all empty (~74%).
    if ((w.x & w.y & w.z & w.w) != -1) {
        const float4 z = make_float4(0.f, 0.f, 0.f, 0.f);
        float4 fx = (w.x >= 0) ? feat4[w.x * 16 + cg] : z;   // chans 4cg..+3
        float4 fy = (w.y >= 0) ? feat4[w.y * 16 + cg] : z;
        float4 fz = (w.z >= 0) ? feat4[w.z * 16 + cg] : z;
        float4 fw = (w.w >= 0) ? feat4[w.w * 16 + cg] : z;
        // 4x4 register transpose: row-major feat -> channel-major out.
        v0 = (nfloat4){fx.x, fy.x, fz.x, fw.x};
        v1 = (nfloat4){fx.y, fy.y, fz.y, fw.y};
        v2 = (nfloat4){fx.z, fy.z, fz.z, fw.z};
        v3 = (nfloat4){fx.w, fy.w, fz.w, fw.w};
    }
    __builtin_nontemporal_store(v0, &out4[base]);
    __builtin_nontemporal_store(v1, &out4[base + (1 << 16)]);
    __builtin_nontemporal_store(v2, &out4[base + (2 << 16)]);
    __builtin_nontemporal_store(v3, &out4[base + (3 << 16)]);
}

extern "C" void kernel_launch(void* const* d_in, const int* in_sizes, int n_in,
                              void* d_out, int out_size, void* d_ws, size_t ws_size,
                              hipStream_t stream) {
    const float* feat  = (const float*)d_in[0];
    const int* coords  = (const int*)d_in[1];

    int n = in_sizes[1] / 3;            // 80000 voxels
    int* winner = (int*)d_ws;           // B*NX*NY ints = 4 MiB scratch

    const int T = 256;
    int B = out_size / (CD * NPIX);     // 4

    int n_win4 = (B * NPIX) / 4;        // 262144
    ppscatter_init_winner<<<(n_win4 + T - 1) / T, T, 0, stream>>>((int4*)winner, n_win4);

    ppscatter_vote<<<(n + T - 1) / T, T, 0, stream>>>(coords, n, winner);

    int n_thr = out_size / 16;          // 4,194,304 threads (4 out4 each)
    ppscatter_gather<<<n_thr / T, T, 0, stream>>>((const float4*)feat,
                                                  (const int4*)winner,
                                                  (nfloat4*)d_out);
}